// Round 4
// baseline (550.885 us; speedup 1.0000x reference)
//
#include <hip/hip_runtime.h>
#include <hip/hip_bf16.h>

#define BIGF 1e30f
#define TC 80   // channels
#define TN 512  // sequence length (N == M)
#define LOG2E 1.44269504088896340736f
#define LN2   0.693147180559945309417f

#define EXP2F(v) __builtin_amdgcn_exp2f(v)   // v_exp_f32 (2^x)
#define LOG2F(v) __builtin_amdgcn_logf(v)    // v_log_f32 (log2 x)

// ---------------------------------------------------------------------------
// Kernel 1: D[b][n][m] = (||x[b,:,n] - y[b,:,m]||^2) * log2(e)
// (base-2 scaled so the DTW kernel can use raw v_exp_f32/v_log_f32)
// 128x128 tile, 256 threads, 8x8 micro-tile as 2x2 blocks of float4.
// Channels staged in two rounds of 40 to stay under 64KB static LDS.
// ---------------------------------------------------------------------------
__global__ __launch_bounds__(256) void pairdist_kernel(
    const float* __restrict__ x, const float* __restrict__ y,
    float* __restrict__ D) {
  const int b  = blockIdx.z;
  const int n0 = blockIdx.x * 128;
  const int m0 = blockIdx.y * 128;

  __shared__ float xs[40][128];
  __shared__ float ys[40][128];
  __shared__ float xxs[128];
  __shared__ float yys[128];

  const float* xb = x + (size_t)b * TC * TN;
  const float* yb = y + (size_t)b * TC * TN;
  const int tid = threadIdx.x;
  const int tm = tid & 15, tn = tid >> 4;

  float acc[2][2][4][4] = {};
  float xxp = 0.f, yyp = 0.f;   // norm partials (threads 0-127: xx, 128-255: yy)

  for (int c0 = 0; c0 < TC; c0 += 40) {
    // stage 40x128 of each, float4-vectorized, coalesced
    for (int i = tid; i < 40 * 32; i += 256) {
      int c = i >> 5, p = i & 31;
      *(float4*)&xs[c][p * 4] = *(const float4*)&xb[(c0 + c) * TN + n0 + p * 4];
      *(float4*)&ys[c][p * 4] = *(const float4*)&yb[(c0 + c) * TN + m0 + p * 4];
    }
    __syncthreads();

    if (tid < 128) {
      for (int c = 0; c < 40; ++c) { float v = xs[c][tid]; xxp += v * v; }
    } else {
      int t2 = tid - 128;
      for (int c = 0; c < 40; ++c) { float v = ys[c][t2]; yyp += v * v; }
    }

    for (int c = 0; c < 40; ++c) {
      float4 xa0 = *(const float4*)&xs[c][tn * 4];
      float4 xa1 = *(const float4*)&xs[c][tn * 4 + 64];
      float4 ya0 = *(const float4*)&ys[c][tm * 4];
      float4 ya1 = *(const float4*)&ys[c][tm * 4 + 64];
      float xv[2][4] = {{xa0.x, xa0.y, xa0.z, xa0.w}, {xa1.x, xa1.y, xa1.z, xa1.w}};
      float yv[2][4] = {{ya0.x, ya0.y, ya0.z, ya0.w}, {ya1.x, ya1.y, ya1.z, ya1.w}};
#pragma unroll
      for (int g = 0; g < 2; ++g)
#pragma unroll
        for (int h = 0; h < 2; ++h)
#pragma unroll
          for (int a = 0; a < 4; ++a)
#pragma unroll
            for (int q = 0; q < 4; ++q)
              acc[g][h][a][q] += xv[g][a] * yv[h][q];
    }
    __syncthreads();
  }

  if (tid < 128) xxs[tid] = xxp; else yys[tid - 128] = yyp;
  __syncthreads();

  float* Dbase = D + (size_t)b * TN * TN;
#pragma unroll
  for (int g = 0; g < 2; ++g)
#pragma unroll
    for (int a = 0; a < 4; ++a) {
      int n = n0 + tn * 4 + a + g * 64;
      float xxv = xxs[tn * 4 + a + g * 64];
#pragma unroll
      for (int h = 0; h < 2; ++h) {
        int m = m0 + tm * 4 + h * 64;
        float4 o;
        o.x = (xxv + yys[tm * 4 + h * 64 + 0] - 2.f * acc[g][h][a][0]) * LOG2E;
        o.y = (xxv + yys[tm * 4 + h * 64 + 1] - 2.f * acc[g][h][a][1]) * LOG2E;
        o.z = (xxv + yys[tm * 4 + h * 64 + 2] - 2.f * acc[g][h][a][2]) * LOG2E;
        o.w = (xxv + yys[tm * 4 + h * 64 + 3] - 2.f * acc[g][h][a][3]) * LOG2E;
        *(float4*)&Dbase[(size_t)n * TN + m] = o;
      }
    }
}

// ---------------------------------------------------------------------------
// Kernel 2: soft-DTW, ONE WAVE per batch. Lane l owns rows i = l*8+1..l*8+8.
// No __syncthreads, no LDS: the only cross-lane dep is one __shfl_up per
// diagonal (lane's top-row value). Ping-pong arrays A/B hold diagonals d-2 and
// d-1; cells computed in DESCENDING k so the in-place overwrite of the d-2
// array is hazard-free and the shfl-consuming cell (k=0) issues last.
// D offsets r*511+(d-2) are always in-bounds -> no clamps; prefetch 1 ahead.
// Recurrence runs in base-2 domain (D pre-scaled by log2e), output * ln2.
// ---------------------------------------------------------------------------
__global__ __launch_bounds__(64) void sdtw_kernel(
    const float* __restrict__ D, float* __restrict__ out) {
  const int b = blockIdx.x;
  const int l = threadIdx.x;  // lane; rows r = l*8+k, k=0..7 (i = r+1)

  const float* Dl = D + (size_t)b * TN * TN + (size_t)(l * 8) * (TN - 1);
  const float* Dp = Dl + 1;   // prefetch pointer: offset (d+1)-2, starts d=3

  float A[8], B[8], dcA[8], dcB[8];
#pragma unroll
  for (int k = 0; k < 8; ++k) { A[k] = BIGF; B[k] = BIGF; }
#pragma unroll
  for (int k = 0; k < 8; ++k) dcA[k] = Dl[k * (TN - 1)];  // d=2 column

  float u0 = (l == 0) ? 0.f : BIGF;  // R_{d-2}[l*8] boundary (lane0: R_0[0]=0)
  int e = -(l * 8);                  // e = (d-2) - l*8; cell k valid iff (unsigned)(e-k)<=511

#define SDTW_BODY(O2, O1, DC, DN, PF)                                     \
  {                                                                       \
    float u1 = __shfl_up(O1[7], 1, 64);                                   \
    u1 = (l == 0) ? BIGF : u1;                                            \
    if (PF) {                                                             \
      _Pragma("unroll")                                                   \
      for (int k = 0; k < 8; ++k) DN[k] = Dp[k * (TN - 1)];               \
      Dp += 1;                                                            \
    }                                                                     \
    _Pragma("unroll")                                                     \
    for (int k = 7; k >= 0; --k) {                                        \
      float r0 = k ? O2[k - 1] : u0;                                      \
      float r1 = k ? O1[k - 1] : u1;                                      \
      float r2 = O1[k];                                                   \
      float m3 = fminf(fminf(r0, r1), r2);                                \
      float s = EXP2F(m3 - r0) + EXP2F(m3 - r1) + EXP2F(m3 - r2);         \
      float sm = m3 - LOG2F(s);                                           \
      float cur = ((unsigned)(e - k) <= (unsigned)(TN - 1))               \
                      ? (DC[k] + sm) : BIGF;                              \
      O2[k] = cur;                                                        \
    }                                                                     \
    u0 = u1;                                                              \
    ++e;                                                                  \
  }

  // d = 2..1024: 511 double-steps + 1 tail (no prefetch past the end)
  for (int it = 0; it < 511; ++it) {
    SDTW_BODY(A, B, dcA, dcB, 1)
    SDTW_BODY(B, A, dcB, dcA, 1)
  }
  SDTW_BODY(A, B, dcA, dcB, 0)
#undef SDTW_BODY

  if (l == 63) out[b] = A[7] * LN2;  // cell (512,512), back to nat units
}

extern "C" void kernel_launch(void* const* d_in, const int* in_sizes, int n_in,
                              void* d_out, int out_size, void* d_ws, size_t ws_size,
                              hipStream_t stream) {
  const float* x = (const float*)d_in[0];
  const float* y = (const float*)d_in[1];
  float* out = (float*)d_out;
  float* D = (float*)d_ws;  // 32*512*512*4 = 33.5 MB

  dim3 g1(TN / 128, TN / 128, 32);
  pairdist_kernel<<<g1, 256, 0, stream>>>(x, y, D);
  sdtw_kernel<<<32, 64, 0, stream>>>(D, out);
}